// Round 1
// baseline (16484.596 us; speedup 1.0000x reference)
//
#include <hip/hip_runtime.h>
#include <hip/hip_bf16.h>
#include <hip/hip_cooperative_groups.h>
#include <cstddef>

namespace cg = cooperative_groups;

#define CC 1024   // states
#define HH 256    // hidden
#define VV 10000  // vocab
#define NN 16     // batch
#define TT 256    // time

__device__ __forceinline__ unsigned short f2bf(float f) {
    unsigned int b = __builtin_bit_cast(unsigned int, f);
    b += 0x7FFFu + ((b >> 16) & 1u);
    return (unsigned short)(b >> 16);
}
__device__ __forceinline__ float bf2f(unsigned short u) {
    return __builtin_bit_cast(float, ((unsigned int)u) << 16);
}

// ---------------- residual MLP: out = relu(relu(x@w1+b1)@w2+b2) + x ----------------
struct ResArgs { const float *x, *w1, *b1, *w2, *b2; float* o; };
struct ResArgs3 { ResArgs a[3]; };

__global__ __launch_bounds__(256) void k_res(ResArgs3 A)
{
    ResArgs R = A.a[blockIdx.y];
    const int r0 = blockIdx.x * 16;
    const int th = threadIdx.x;
    __shared__ float xs[256][24];   // [h][r] transposed, padded
    __shared__ float hs[256][24];
    #pragma unroll
    for (int k = 0; k < 16; k++) xs[th][k] = R.x[(size_t)(r0 + k) * HH + th];
    __syncthreads();
    float acc[16];
    float b1v = R.b1[th];
    #pragma unroll
    for (int r = 0; r < 16; r++) acc[r] = b1v;
    for (int h = 0; h < HH; h++) {
        float w = R.w1[(size_t)h * HH + th];
        #pragma unroll
        for (int r = 0; r < 16; r++) acc[r] = fmaf(xs[h][r], w, acc[r]);
    }
    #pragma unroll
    for (int r = 0; r < 16; r++) hs[th][r] = fmaxf(acc[r], 0.f);
    __syncthreads();
    float b2v = R.b2[th];
    #pragma unroll
    for (int r = 0; r < 16; r++) acc[r] = b2v;
    for (int h = 0; h < HH; h++) {
        float w = R.w2[(size_t)h * HH + th];
        #pragma unroll
        for (int r = 0; r < 16; r++) acc[r] = fmaf(hs[h][r], w, acc[r]);
    }
    #pragma unroll
    for (int r = 0; r < 16; r++) {
        size_t idx = (size_t)(r0 + r) * HH + th;
        R.o[idx] = fmaxf(acc[r], 0.f) + R.x[idx];
    }
}

// ---------------- start logits: slog[c] = res_s[c,:]@sw3 + sb3 ----------------
__global__ __launch_bounds__(256) void k_slog(const float* __restrict__ res_s,
                                              const float* __restrict__ sw3,
                                              const float* __restrict__ sb3,
                                              float* __restrict__ slog)
{
    __shared__ float wv[256];
    const int th = threadIdx.x;
    const int c = blockIdx.x * 256 + th;
    wv[th] = sw3[th];
    __syncthreads();
    const float* row = res_s + (size_t)c * HH;
    float acc = 0.f;
    for (int h = 0; h < HH; h++) acc = fmaf(row[h], wv[h], acc);
    slog[c] = acc + sb3[0];
}

// ---------------- transition: PT[i][j] = softmax_j(res_t[i,:]@tw3 + tb3) ----------------
__global__ __launch_bounds__(256) void k_pt(const float* __restrict__ res_t,
                                            const float* __restrict__ tw3,
                                            const float* __restrict__ tb3,
                                            float* __restrict__ PT)
{
    const int r0 = blockIdx.x * 4;
    const int th = threadIdx.x;
    __shared__ float rs[4][256];
    __shared__ float sred[256];
    for (int k = 0; k < 4; k++) rs[k][th] = res_t[(size_t)(r0 + k) * HH + th];
    __syncthreads();
    float acc[4][4];
    #pragma unroll
    for (int r = 0; r < 4; r++)
        #pragma unroll
        for (int q = 0; q < 4; q++) acc[r][q] = tb3[th + q * 256];
    for (int h = 0; h < HH; h++) {
        float w0 = tw3[(size_t)h * CC + th];
        float w1 = tw3[(size_t)h * CC + th + 256];
        float w2 = tw3[(size_t)h * CC + th + 512];
        float w3 = tw3[(size_t)h * CC + th + 768];
        #pragma unroll
        for (int r = 0; r < 4; r++) {
            float xv = rs[r][h];
            acc[r][0] = fmaf(xv, w0, acc[r][0]);
            acc[r][1] = fmaf(xv, w1, acc[r][1]);
            acc[r][2] = fmaf(xv, w2, acc[r][2]);
            acc[r][3] = fmaf(xv, w3, acc[r][3]);
        }
    }
    for (int r = 0; r < 4; r++) {
        float m = fmaxf(fmaxf(acc[r][0], acc[r][1]), fmaxf(acc[r][2], acc[r][3]));
        sred[th] = m; __syncthreads();
        for (int off = 128; off > 0; off >>= 1) { if (th < off) sred[th] = fmaxf(sred[th], sred[th + off]); __syncthreads(); }
        float rm = sred[0]; __syncthreads();
        float ssum = __expf(acc[r][0] - rm) + __expf(acc[r][1] - rm) + __expf(acc[r][2] - rm) + __expf(acc[r][3] - rm);
        sred[th] = ssum; __syncthreads();
        for (int off = 128; off > 0; off >>= 1) { if (th < off) sred[th] += sred[th + off]; __syncthreads(); }
        float inv = 1.0f / sred[0]; __syncthreads();
        #pragma unroll
        for (int q = 0; q < 4; q++)
            PT[(size_t)(r0 + r) * CC + th + q * 256] = __expf(acc[r][q] - rm) * inv;
    }
}

// ---------------- emission: emitT[v][c] = logits (bf16), epart[chunk][c] = {max,sumexp} ----------------
__global__ __launch_bounds__(256) void k_emit(const float* __restrict__ res_e,
                                              const float* __restrict__ ew3,
                                              const float* __restrict__ eb3,
                                              unsigned short* __restrict__ emitT,
                                              float* __restrict__ epart)
{
    const int ct = blockIdx.x >> 2, jc = blockIdx.x & 3;
    const int c0 = ct * 16, j0 = jc * 2500;
    const int th = threadIdx.x;
    __shared__ float rs[256][24];   // [h][c]
    __shared__ float sred[256];
    for (int k = 0; k < 16; k++) rs[th][k] = res_e[(size_t)(c0 + k) * HH + th];
    __syncthreads();
    float lm[16], ls[16];
    #pragma unroll
    for (int c = 0; c < 16; c++) { lm[c] = -1e30f; ls[c] = 0.f; }
    for (int it = 0; it < 10; it++) {
        int jo = it * 256 + th;
        if (jo < 2500) {
            int j = j0 + jo;
            float acc[16];
            float bb = eb3[j];
            #pragma unroll
            for (int c = 0; c < 16; c++) acc[c] = bb;
            for (int h = 0; h < HH; h++) {
                float wv = ew3[(size_t)h * VV + j];
                #pragma unroll
                for (int c = 0; c < 16; c++) acc[c] = fmaf(rs[h][c], wv, acc[c]);
            }
            #pragma unroll
            for (int c = 0; c < 16; c++) {
                emitT[(size_t)j * CC + c0 + c] = f2bf(acc[c]);
                float nm = fmaxf(lm[c], acc[c]);
                ls[c] = ls[c] * __expf(lm[c] - nm) + __expf(acc[c] - nm);
                lm[c] = nm;
            }
        }
    }
    for (int c = 0; c < 16; c++) {
        sred[th] = lm[c]; __syncthreads();
        for (int off = 128; off > 0; off >>= 1) { if (th < off) sred[th] = fmaxf(sred[th], sred[th + off]); __syncthreads(); }
        float gm = sred[0]; __syncthreads();
        sred[th] = (lm[c] > -1e29f) ? ls[c] * __expf(lm[c] - gm) : 0.f;
        __syncthreads();
        for (int off = 128; off > 0; off >>= 1) { if (th < off) sred[th] += sred[th + off]; __syncthreads(); }
        if (th == 0) {
            epart[((size_t)jc * CC + c0 + c) * 2]     = gm;
            epart[((size_t)jc * CC + c0 + c) * 2 + 1] = sred[0];
        }
        __syncthreads();
    }
}

// ---------------- forward scan (cooperative, persistent) ----------------
// 256 blocks = 16 seqs x 16 j-slices(64). Each thread holds P[16i x 8j] in regs.
__global__ void __launch_bounds__(512, 2) k_scan(
    const float* __restrict__ PT, const unsigned short* __restrict__ emitT,
    const float* __restrict__ epart, const float* __restrict__ slog,
    const int* __restrict__ text, float* __restrict__ alpha, float* __restrict__ bm,
    float* __restrict__ outpart, float* __restrict__ out)
{
    cg::grid_group grid = cg::this_grid();
    const int b = blockIdx.x;
    const int n = b >> 4, s = b & 15;
    const int j0 = s * 64;
    const int th = threadIdx.x;
    const int jg = th & 7;    // 0..7 -> 8 j's each
    const int ig = th >> 3;   // 0..63 -> 16 i's each
    __shared__ float a2[64 * 17];     // exp(alpha - M), skewed [i/16][i%16]
    __shared__ float red[64 * 65];    // partials [jj][ig]
    __shared__ float red2[64 * 9];    // [jj][seg]
    __shared__ float lsel[64];
    __shared__ float sred[512];
    __shared__ float scl[1];

    // emission LSE for our 64 states
    if (th < 64) {
        float M = -1e30f, S = 0.f;
        for (int q = 0; q < 4; q++) {
            const float* pp = epart + ((size_t)q * CC + j0 + th) * 2;
            float m = pp[0], s2 = pp[1];
            float nm = fmaxf(M, m);
            S = S * __expf(M - nm) + s2 * __expf(m - nm);
            M = nm;
        }
        lsel[th] = M + __logf(S);
    }
    // start LSE (redundant per block)
    float lv = fmaxf(slog[th], slog[th + 512]);
    sred[th] = lv; __syncthreads();
    for (int off = 256; off > 0; off >>= 1) { if (th < off) sred[th] = fmaxf(sred[th], sred[th + off]); __syncthreads(); }
    float smax = sred[0]; __syncthreads();
    float ls2 = __expf(slog[th] - smax) + __expf(slog[th + 512] - smax);
    sred[th] = ls2; __syncthreads();
    for (int off = 256; off > 0; off >>= 1) { if (th < off) sred[th] += sred[th + off]; __syncthreads(); }
    float slse = smax + __logf(sred[0]);
    __syncthreads();

    // load P slice into registers: pt[ii][v] = PT[ig*16+ii][j0 + jg*8 + v]
    float pt[16][8];
    #pragma unroll
    for (int ii = 0; ii < 16; ii++) {
        const float* prow = PT + (size_t)(ig * 16 + ii) * CC + j0 + jg * 8;
        #pragma unroll
        for (int v = 0; v < 8; v++) pt[ii][v] = prow[v];
    }

    // t = 0
    {
        int tok = text[n * TT];
        if (th < 64) {
            float v0 = slog[j0 + th] - slse + bf2f(emitT[(size_t)tok * CC + j0 + th]) - lsel[th];
            alpha[(size_t)n * CC + j0 + th] = v0;   // buffer 0
            float m = v0;
            #pragma unroll
            for (int off = 1; off < 64; off <<= 1) m = fmaxf(m, __shfl_xor(m, off));
            if (th == 0) bm[n * 16 + s] = m;
        }
    }
    __threadfence();
    grid.sync();

    for (int t = 1; t < TT; t++) {
        const int cur = t & 1, prv = cur ^ 1;
        const float* ap = alpha + (size_t)prv * NN * CC + (size_t)n * CC;
        if (th < 16) {
            float m = bm[prv * NN * 16 + n * 16 + th];
            #pragma unroll
            for (int off = 1; off < 16; off <<= 1) m = fmaxf(m, __shfl_xor(m, off));
            if (th == 0) scl[0] = m;
        }
        __syncthreads();
        const float M = scl[0];
        {
            int i = th * 2;
            a2[(i >> 4) * 17 + (i & 15)]             = __expf(ap[i] - M);
            a2[((i + 1) >> 4) * 17 + ((i + 1) & 15)] = __expf(ap[i + 1] - M);
        }
        __syncthreads();
        float acc[8];
        #pragma unroll
        for (int v = 0; v < 8; v++) acc[v] = 0.f;
        #pragma unroll
        for (int ii = 0; ii < 16; ii++) {
            float av = a2[ig * 17 + ii];
            #pragma unroll
            for (int v = 0; v < 8; v++) acc[v] = fmaf(av, pt[ii][v], acc[v]);
        }
        #pragma unroll
        for (int v = 0; v < 8; v++) red[(jg * 8 + v) * 65 + ig] = acc[v];
        __syncthreads();
        {
            int jj = th & 63, seg = th >> 6;
            float p = 0.f;
            #pragma unroll
            for (int k = 0; k < 8; k++) p += red[jj * 65 + seg * 8 + k];
            red2[jj * 9 + seg] = p;
        }
        __syncthreads();
        int tok = text[n * TT + t];
        if (th < 64) {
            float d = 0.f;
            #pragma unroll
            for (int k2 = 0; k2 < 8; k2++) d += red2[th * 9 + k2];
            float vv = M + __logf(d) + bf2f(emitT[(size_t)tok * CC + j0 + th]) - lsel[th];
            alpha[(size_t)cur * NN * CC + (size_t)n * CC + j0 + th] = vv;
            float m = vv;
            #pragma unroll
            for (int off = 1; off < 64; off <<= 1) m = fmaxf(m, __shfl_xor(m, off));
            if (th == 0) bm[cur * NN * 16 + n * 16 + s] = m;
        }
        __threadfence();
        grid.sync();
    }

    // final logsumexp per sequence (alpha buffer 1 holds t = T-1)
    if (s == 0) {
        if (th < 16) {
            float m = bm[1 * NN * 16 + n * 16 + th];
            #pragma unroll
            for (int off = 1; off < 16; off <<= 1) m = fmaxf(m, __shfl_xor(m, off));
            if (th == 0) scl[0] = m;
        }
        __syncthreads();
        float M = scl[0];
        float ssum = __expf(alpha[(size_t)NN * CC + (size_t)n * CC + th] - M)
                   + __expf(alpha[(size_t)NN * CC + (size_t)n * CC + th + 512] - M);
        sred[th] = ssum; __syncthreads();
        for (int off = 256; off > 0; off >>= 1) { if (th < off) sred[th] += sred[th + off]; __syncthreads(); }
        if (th == 0) outpart[n] = M + __logf(sred[0]);
    }
    __threadfence();
    grid.sync();
    if (b == 0 && th == 0) {
        float o = 0.f;
        for (int nn = 0; nn < NN; nn++) o += outpart[nn];
        out[0] = o;
    }
}

extern "C" void kernel_launch(void* const* d_in, const int* in_sizes, int n_in,
                              void* d_out, int out_size, void* d_ws, size_t ws_size,
                              hipStream_t stream) {
    const int*   text      = (const int*)  d_in[0];
    const float* start_emb = (const float*)d_in[1];
    const float* sw1 = (const float*)d_in[2];
    const float* sb1 = (const float*)d_in[3];
    const float* sw2 = (const float*)d_in[4];
    const float* sb2 = (const float*)d_in[5];
    const float* sw3 = (const float*)d_in[6];
    const float* sb3 = (const float*)d_in[7];
    const float* state_emb = (const float*)d_in[8];
    const float* tw1 = (const float*)d_in[9];
    const float* tb1 = (const float*)d_in[10];
    const float* tw2 = (const float*)d_in[11];
    const float* tb2 = (const float*)d_in[12];
    const float* tw3 = (const float*)d_in[13];
    const float* tb3 = (const float*)d_in[14];
    const float* pre_emb = (const float*)d_in[15];
    const float* ew1 = (const float*)d_in[16];
    const float* eb1 = (const float*)d_in[17];
    const float* ew2 = (const float*)d_in[18];
    const float* eb2 = (const float*)d_in[19];
    const float* ew3 = (const float*)d_in[20];
    const float* eb3 = (const float*)d_in[21];

    char* w = (char*)d_ws;
    float* res_s = (float*)(w + (size_t)(0 << 20));
    float* res_t = (float*)(w + (size_t)(1 << 20));
    float* res_e = (float*)(w + (size_t)(2 << 20));
    float* slog  = (float*)(w + (size_t)(3 << 20));
    float* PT    = (float*)(w + (size_t)(4 << 20));
    unsigned short* emitT = (unsigned short*)(w + (size_t)(8 << 20));   // 20.48 MB
    float* epart = (float*)(w + (size_t)(29 << 20));                    // 32 KB
    float* alpha = (float*)(w + (size_t)(30 << 20));                    // 128 KB
    float* bm    = (float*)(w + (size_t)(30 << 20) + 200 * 1024);       // 2 KB
    float* outpart = (float*)(w + (size_t)(30 << 20) + 300 * 1024);     // 64 B
    float* outp  = (float*)d_out;

    if (ws_size < ((size_t)31 << 20)) return;  // leaves poison -> visible failure

    ResArgs3 ra;
    ra.a[0] = { start_emb, sw1, sb1, sw2, sb2, res_s };
    ra.a[1] = { state_emb, tw1, tb1, tw2, tb2, res_t };
    ra.a[2] = { pre_emb,   ew1, eb1, ew2, eb2, res_e };

    hipLaunchKernelGGL(k_res,  dim3(64, 3), dim3(256), 0, stream, ra);
    hipLaunchKernelGGL(k_slog, dim3(4),     dim3(256), 0, stream, res_s, sw3, sb3, slog);
    hipLaunchKernelGGL(k_pt,   dim3(256),   dim3(256), 0, stream, res_t, tw3, tb3, PT);
    hipLaunchKernelGGL(k_emit, dim3(256),   dim3(256), 0, stream, res_e, ew3, eb3, emitT, epart);

    void* kargs[] = { (void*)&PT, (void*)&emitT, (void*)&epart, (void*)&slog, (void*)&text,
                      (void*)&alpha, (void*)&bm, (void*)&outpart, (void*)&outp };
    hipLaunchCooperativeKernel((const void*)k_scan, dim3(256), dim3(512), kargs, 0, stream);
}

// Round 2
// 8009.023 us; speedup vs baseline: 2.0583x; 2.0583x over previous
//
#include <hip/hip_runtime.h>
#include <hip/hip_bf16.h>
#include <cstddef>

#define CC 1024   // states
#define HH 256    // hidden
#define VV 10000  // vocab
#define NN 16     // batch
#define TT 256    // time

__device__ __forceinline__ unsigned short f2bf(float f) {
    unsigned int b = __builtin_bit_cast(unsigned int, f);
    b += 0x7FFFu + ((b >> 16) & 1u);
    return (unsigned short)(b >> 16);
}
__device__ __forceinline__ float bf2f(unsigned short u) {
    return __builtin_bit_cast(float, ((unsigned int)u) << 16);
}

// ---------------- residual MLP: out = relu(relu(x@w1+b1)@w2+b2) + x ----------------
struct ResArgs { const float *x, *w1, *b1, *w2, *b2; float* o; };
struct ResArgs3 { ResArgs a[3]; };

__global__ __launch_bounds__(256) void k_res(ResArgs3 A)
{
    ResArgs R = A.a[blockIdx.y];
    const int r0 = blockIdx.x * 16;
    const int th = threadIdx.x;
    __shared__ float xs[256][24];   // [h][r] transposed, padded
    __shared__ float hs[256][24];
    #pragma unroll
    for (int k = 0; k < 16; k++) xs[th][k] = R.x[(size_t)(r0 + k) * HH + th];
    __syncthreads();
    float acc[16];
    float b1v = R.b1[th];
    #pragma unroll
    for (int r = 0; r < 16; r++) acc[r] = b1v;
    for (int h = 0; h < HH; h++) {
        float w = R.w1[(size_t)h * HH + th];
        #pragma unroll
        for (int r = 0; r < 16; r++) acc[r] = fmaf(xs[h][r], w, acc[r]);
    }
    #pragma unroll
    for (int r = 0; r < 16; r++) hs[th][r] = fmaxf(acc[r], 0.f);
    __syncthreads();
    float b2v = R.b2[th];
    #pragma unroll
    for (int r = 0; r < 16; r++) acc[r] = b2v;
    for (int h = 0; h < HH; h++) {
        float w = R.w2[(size_t)h * HH + th];
        #pragma unroll
        for (int r = 0; r < 16; r++) acc[r] = fmaf(hs[h][r], w, acc[r]);
    }
    #pragma unroll
    for (int r = 0; r < 16; r++) {
        size_t idx = (size_t)(r0 + r) * HH + th;
        R.o[idx] = fmaxf(acc[r], 0.f) + R.x[idx];
    }
}

// ---------------- start logits: slog[c] = res_s[c,:]@sw3 + sb3 ----------------
__global__ __launch_bounds__(256) void k_slog(const float* __restrict__ res_s,
                                              const float* __restrict__ sw3,
                                              const float* __restrict__ sb3,
                                              float* __restrict__ slog)
{
    __shared__ float wv[256];
    const int th = threadIdx.x;
    const int c = blockIdx.x * 256 + th;
    wv[th] = sw3[th];
    __syncthreads();
    const float* row = res_s + (size_t)c * HH;
    float acc = 0.f;
    for (int h = 0; h < HH; h++) acc = fmaf(row[h], wv[h], acc);
    slog[c] = acc + sb3[0];
}

// ---------------- transition: PT[i][j] = softmax_j(res_t[i,:]@tw3 + tb3), row i = prev ----------------
__global__ __launch_bounds__(256) void k_pt(const float* __restrict__ res_t,
                                            const float* __restrict__ tw3,
                                            const float* __restrict__ tb3,
                                            float* __restrict__ PT)
{
    const int r0 = blockIdx.x * 4;
    const int th = threadIdx.x;
    __shared__ float rs[4][256];
    __shared__ float sred[256];
    for (int k = 0; k < 4; k++) rs[k][th] = res_t[(size_t)(r0 + k) * HH + th];
    __syncthreads();
    float acc[4][4];
    #pragma unroll
    for (int r = 0; r < 4; r++)
        #pragma unroll
        for (int q = 0; q < 4; q++) acc[r][q] = tb3[th + q * 256];
    for (int h = 0; h < HH; h++) {
        float w0 = tw3[(size_t)h * CC + th];
        float w1 = tw3[(size_t)h * CC + th + 256];
        float w2 = tw3[(size_t)h * CC + th + 512];
        float w3 = tw3[(size_t)h * CC + th + 768];
        #pragma unroll
        for (int r = 0; r < 4; r++) {
            float xv = rs[r][h];
            acc[r][0] = fmaf(xv, w0, acc[r][0]);
            acc[r][1] = fmaf(xv, w1, acc[r][1]);
            acc[r][2] = fmaf(xv, w2, acc[r][2]);
            acc[r][3] = fmaf(xv, w3, acc[r][3]);
        }
    }
    for (int r = 0; r < 4; r++) {
        float m = fmaxf(fmaxf(acc[r][0], acc[r][1]), fmaxf(acc[r][2], acc[r][3]));
        sred[th] = m; __syncthreads();
        for (int off = 128; off > 0; off >>= 1) { if (th < off) sred[th] = fmaxf(sred[th], sred[th + off]); __syncthreads(); }
        float rm = sred[0]; __syncthreads();
        float ssum = __expf(acc[r][0] - rm) + __expf(acc[r][1] - rm) + __expf(acc[r][2] - rm) + __expf(acc[r][3] - rm);
        sred[th] = ssum; __syncthreads();
        for (int off = 128; off > 0; off >>= 1) { if (th < off) sred[th] += sred[th + off]; __syncthreads(); }
        float inv = 1.0f / sred[0]; __syncthreads();
        #pragma unroll
        for (int q = 0; q < 4; q++)
            PT[(size_t)(r0 + r) * CC + th + q * 256] = __expf(acc[r][q] - rm) * inv;
    }
}

// ---------------- emission: emitT[v][c] = logits (bf16), epart[chunk][c] = {max,sumexp} ----------------
__global__ __launch_bounds__(256) void k_emit(const float* __restrict__ res_e,
                                              const float* __restrict__ ew3,
                                              const float* __restrict__ eb3,
                                              unsigned short* __restrict__ emitT,
                                              float* __restrict__ epart)
{
    const int ct = blockIdx.x >> 2, jc = blockIdx.x & 3;
    const int c0 = ct * 16, j0 = jc * 2500;
    const int th = threadIdx.x;
    __shared__ float rs[256][24];   // [h][c]
    __shared__ float sred[256];
    for (int k = 0; k < 16; k++) rs[th][k] = res_e[(size_t)(c0 + k) * HH + th];
    __syncthreads();
    float lm[16], ls[16];
    #pragma unroll
    for (int c = 0; c < 16; c++) { lm[c] = -1e30f; ls[c] = 0.f; }
    for (int it = 0; it < 10; it++) {
        int jo = it * 256 + th;
        if (jo < 2500) {
            int j = j0 + jo;
            float acc[16];
            float bb = eb3[j];
            #pragma unroll
            for (int c = 0; c < 16; c++) acc[c] = bb;
            for (int h = 0; h < HH; h++) {
                float wv = ew3[(size_t)h * VV + j];
                #pragma unroll
                for (int c = 0; c < 16; c++) acc[c] = fmaf(rs[h][c], wv, acc[c]);
            }
            #pragma unroll
            for (int c = 0; c < 16; c++) {
                emitT[(size_t)j * CC + c0 + c] = f2bf(acc[c]);
                float nm = fmaxf(lm[c], acc[c]);
                ls[c] = ls[c] * __expf(lm[c] - nm) + __expf(acc[c] - nm);
                lm[c] = nm;
            }
        }
    }
    for (int c = 0; c < 16; c++) {
        sred[th] = lm[c]; __syncthreads();
        for (int off = 128; off > 0; off >>= 1) { if (th < off) sred[th] = fmaxf(sred[th], sred[th + off]); __syncthreads(); }
        float gm = sred[0]; __syncthreads();
        sred[th] = (lm[c] > -1e29f) ? ls[c] * __expf(lm[c] - gm) : 0.f;
        __syncthreads();
        for (int off = 128; off > 0; off >>= 1) { if (th < off) sred[th] += sred[th + off]; __syncthreads(); }
        if (th == 0) {
            epart[((size_t)jc * CC + c0 + c) * 2]     = gm;
            epart[((size_t)jc * CC + c0 + c) * 2 + 1] = sred[0];
        }
        __syncthreads();
    }
}

// ---------------- block-level sum over 1024 threads ----------------
__device__ __forceinline__ float blocksum(float v, float* sred, float* bc, int wv, int lane)
{
    #pragma unroll
    for (int o = 32; o; o >>= 1) v += __shfl_xor(v, o);
    if (lane == 0) sred[wv] = v;
    __syncthreads();
    if (wv == 0) {
        float s = sred[lane & 15];
        #pragma unroll
        for (int o = 8; o; o >>= 1) s += __shfl_xor(s, o);
        if (lane == 0) bc[0] = s;
    }
    __syncthreads();
    return bc[0];
}

// ---------------- scaled forward scan: 1 block = 1 sequence, alpha in LDS ----------------
// thread = (wv = th>>6 -> i in [wv*64, wv*64+64), lane -> j in {q*256 + lane*4 + e})
__global__ void __launch_bounds__(1024, 1) k_fwd(
    const float* __restrict__ PT, const unsigned short* __restrict__ emitT,
    const float* __restrict__ epart, const float* __restrict__ slog,
    const int* __restrict__ text, float* __restrict__ outpart)
{
    const int n = blockIdx.x;
    const int th = threadIdx.x;
    const int wv = th >> 6;
    const int lane = th & 63;
    __shared__ float a_sh[1024];
    __shared__ float red[16][1028];   // 16-B aligned rows (4112 B), +4 pad vs 1024
    __shared__ float lse_s[1024];
    __shared__ float sred[16];
    __shared__ float bc[1];

    // emission LSE per state (combine 4 chunk partials)
    {
        float M = -1e30f, S = 0.f;
        #pragma unroll
        for (int q = 0; q < 4; q++) {
            float m  = epart[((size_t)q * CC + th) * 2];
            float s2 = epart[((size_t)q * CC + th) * 2 + 1];
            float nm = fmaxf(M, m);
            S = S * __expf(M - nm) + s2 * __expf(m - nm);
            M = nm;
        }
        lse_s[th] = M + __logf(S);
    }

    // p0 = softmax(slog)  (block max then block sum)
    float sl = slog[th];
    float m = sl;
    #pragma unroll
    for (int o = 32; o; o >>= 1) m = fmaxf(m, __shfl_xor(m, o));
    if (lane == 0) sred[wv] = m;
    __syncthreads();
    if (wv == 0) {
        float mm = sred[lane & 15];
        #pragma unroll
        for (int o = 8; o; o >>= 1) mm = fmaxf(mm, __shfl_xor(mm, o));
        if (lane == 0) bc[0] = mm;
    }
    __syncthreads();
    float M0 = bc[0];
    __syncthreads();
    float ex = __expf(sl - M0);
    float ssum = blocksum(ex, sred, bc, wv, lane);
    float p0 = ex / ssum;

    float logacc;
    {   // t = 0
        int tok = text[n * TT];
        float e0 = __expf(bf2f(emitT[(size_t)tok * CC + th]) - lse_s[th]);
        float v = p0 * e0;
        float S = blocksum(v, sred, bc, wv, lane);
        a_sh[th] = v / S;
        logacc = __logf(S);
    }
    __syncthreads();

    const char* pbase = (const char*)PT + ((size_t)wv * 64) * (CC * 4) + (size_t)lane * 16;

    for (int t = 1; t < TT; t++) {
        float acc[16];
        #pragma unroll
        for (int q = 0; q < 16; q++) acc[q] = 0.f;
        const char* pb = pbase;
        #pragma unroll 1
        for (int ii = 0; ii < 64; ii += 4) {
            float4 av = *(const float4*)&a_sh[wv * 64 + ii];
            #pragma unroll
            for (int u = 0; u < 4; u++) {
                const float* pr = (const float*)(pb + (size_t)u * (CC * 4));
                float aa = (u == 0) ? av.x : (u == 1) ? av.y : (u == 2) ? av.z : av.w;
                #pragma unroll
                for (int q = 0; q < 4; q++) {
                    float4 pv = *(const float4*)(pr + q * 256);
                    acc[q * 4 + 0] = fmaf(aa, pv.x, acc[q * 4 + 0]);
                    acc[q * 4 + 1] = fmaf(aa, pv.y, acc[q * 4 + 1]);
                    acc[q * 4 + 2] = fmaf(aa, pv.z, acc[q * 4 + 2]);
                    acc[q * 4 + 3] = fmaf(aa, pv.w, acc[q * 4 + 3]);
                }
            }
            pb += 4 * (CC * 4);
        }
        #pragma unroll
        for (int q = 0; q < 4; q++)
            *(float4*)&red[wv][q * 256 + lane * 4] =
                make_float4(acc[q * 4], acc[q * 4 + 1], acc[q * 4 + 2], acc[q * 4 + 3]);
        __syncthreads();
        float y = 0.f;
        #pragma unroll
        for (int k = 0; k < 16; k++) y += red[k][th];
        int tok = text[n * TT + t];
        float e = __expf(bf2f(emitT[(size_t)tok * CC + th]) - lse_s[th]);
        float v = y * e;
        float S = blocksum(v, sred, bc, wv, lane);
        logacc += __logf(S);
        a_sh[th] = v / S;
        __syncthreads();
    }

    if (th == 0) outpart[n] = logacc;
}

__global__ void k_final(const float* __restrict__ outpart, float* __restrict__ out)
{
    if (threadIdx.x == 0 && blockIdx.x == 0) {
        float s = 0.f;
        for (int i = 0; i < NN; i++) s += outpart[i];
        out[0] = s;
    }
}

extern "C" void kernel_launch(void* const* d_in, const int* in_sizes, int n_in,
                              void* d_out, int out_size, void* d_ws, size_t ws_size,
                              hipStream_t stream) {
    const int*   text      = (const int*)  d_in[0];
    const float* start_emb = (const float*)d_in[1];
    const float* sw1 = (const float*)d_in[2];
    const float* sb1 = (const float*)d_in[3];
    const float* sw2 = (const float*)d_in[4];
    const float* sb2 = (const float*)d_in[5];
    const float* sw3 = (const float*)d_in[6];
    const float* sb3 = (const float*)d_in[7];
    const float* state_emb = (const float*)d_in[8];
    const float* tw1 = (const float*)d_in[9];
    const float* tb1 = (const float*)d_in[10];
    const float* tw2 = (const float*)d_in[11];
    const float* tb2 = (const float*)d_in[12];
    const float* tw3 = (const float*)d_in[13];
    const float* tb3 = (const float*)d_in[14];
    const float* pre_emb = (const float*)d_in[15];
    const float* ew1 = (const float*)d_in[16];
    const float* eb1 = (const float*)d_in[17];
    const float* ew2 = (const float*)d_in[18];
    const float* eb2 = (const float*)d_in[19];
    const float* ew3 = (const float*)d_in[20];
    const float* eb3 = (const float*)d_in[21];

    char* w = (char*)d_ws;
    float* res_s = (float*)(w + (size_t)(0 << 20));
    float* res_t = (float*)(w + (size_t)(1 << 20));
    float* res_e = (float*)(w + (size_t)(2 << 20));
    float* slog  = (float*)(w + (size_t)(3 << 20));
    float* PT    = (float*)(w + (size_t)(4 << 20));                     // 4 MB fp32
    unsigned short* emitT = (unsigned short*)(w + (size_t)(8 << 20));   // 20.48 MB bf16
    float* epart = (float*)(w + (size_t)(29 << 20));                    // 32 KB
    float* outpart = (float*)(w + (size_t)(30 << 20) + 300 * 1024);     // 64 B
    float* outp  = (float*)d_out;

    if (ws_size < ((size_t)31 << 20)) return;  // leaves poison -> visible failure

    ResArgs3 ra;
    ra.a[0] = { start_emb, sw1, sb1, sw2, sb2, res_s };
    ra.a[1] = { state_emb, tw1, tb1, tw2, tb2, res_t };
    ra.a[2] = { pre_emb,   ew1, eb1, ew2, eb2, res_e };

    hipLaunchKernelGGL(k_res,  dim3(64, 3), dim3(256), 0, stream, ra);
    hipLaunchKernelGGL(k_slog, dim3(4),     dim3(256), 0, stream, res_s, sw3, sb3, slog);
    hipLaunchKernelGGL(k_pt,   dim3(256),   dim3(256), 0, stream, res_t, tw3, tb3, PT);
    hipLaunchKernelGGL(k_emit, dim3(256),   dim3(256), 0, stream, res_e, ew3, eb3, emitT, epart);
    hipLaunchKernelGGL(k_fwd,  dim3(NN),    dim3(1024), 0, stream, PT, emitT, epart, slog, text, outpart);
    hipLaunchKernelGGL(k_final,dim3(1),     dim3(64),  0, stream, outpart, outp);
}

// Round 3
// 2887.300 us; speedup vs baseline: 5.7093x; 2.7739x over previous
//
#include <hip/hip_runtime.h>
#include <hip/hip_bf16.h>
#include <cstddef>

#define CC 1024   // states
#define HH 256    // hidden
#define VV 10000  // vocab
#define NN 16     // batch
#define TT 256    // time
#define NB 16     // blocks in k_fwd

typedef __attribute__((ext_vector_type(8))) short s8b;
typedef __attribute__((ext_vector_type(4))) float f32x4;

__device__ __forceinline__ unsigned short f2bf(float f) {
    unsigned int b = __builtin_bit_cast(unsigned int, f);
    b += 0x7FFFu + ((b >> 16) & 1u);
    return (unsigned short)(b >> 16);
}
__device__ __forceinline__ float bf2f(unsigned short u) {
    return __builtin_bit_cast(float, ((unsigned int)u) << 16);
}

// ---------------- residual MLP: out = relu(relu(x@w1+b1)@w2+b2) + x ----------------
struct ResArgs { const float *x, *w1, *b1, *w2, *b2; float* o; };
struct ResArgs3 { ResArgs a[3]; };

__global__ __launch_bounds__(256) void k_res(ResArgs3 A)
{
    ResArgs R = A.a[blockIdx.y];
    const int r0 = blockIdx.x * 16;
    const int th = threadIdx.x;
    __shared__ float xs[256][24];
    __shared__ float hs[256][24];
    #pragma unroll
    for (int k = 0; k < 16; k++) xs[th][k] = R.x[(size_t)(r0 + k) * HH + th];
    __syncthreads();
    float acc[16];
    float b1v = R.b1[th];
    #pragma unroll
    for (int r = 0; r < 16; r++) acc[r] = b1v;
    for (int h = 0; h < HH; h++) {
        float w = R.w1[(size_t)h * HH + th];
        #pragma unroll
        for (int r = 0; r < 16; r++) acc[r] = fmaf(xs[h][r], w, acc[r]);
    }
    #pragma unroll
    for (int r = 0; r < 16; r++) hs[th][r] = fmaxf(acc[r], 0.f);
    __syncthreads();
    float b2v = R.b2[th];
    #pragma unroll
    for (int r = 0; r < 16; r++) acc[r] = b2v;
    for (int h = 0; h < HH; h++) {
        float w = R.w2[(size_t)h * HH + th];
        #pragma unroll
        for (int r = 0; r < 16; r++) acc[r] = fmaf(hs[h][r], w, acc[r]);
    }
    #pragma unroll
    for (int r = 0; r < 16; r++) {
        size_t idx = (size_t)(r0 + r) * HH + th;
        R.o[idx] = fmaxf(acc[r], 0.f) + R.x[idx];
    }
}

// ---------------- start logits ----------------
__global__ __launch_bounds__(256) void k_slog(const float* __restrict__ res_s,
                                              const float* __restrict__ sw3,
                                              const float* __restrict__ sb3,
                                              float* __restrict__ slog)
{
    __shared__ float wv[256];
    const int th = threadIdx.x;
    const int c = blockIdx.x * 256 + th;
    wv[th] = sw3[th];
    __syncthreads();
    const float* row = res_s + (size_t)c * HH;
    float acc = 0.f;
    for (int h = 0; h < HH; h++) acc = fmaf(row[h], wv[h], acc);
    slog[c] = acc + sb3[0];
}

// ---------------- transition probs, transposed bf16: PB[j][i] = p(j | i) ----------------
__global__ __launch_bounds__(256) void k_pt(const float* __restrict__ res_t,
                                            const float* __restrict__ tw3,
                                            const float* __restrict__ tb3,
                                            unsigned short* __restrict__ PB)
{
    const int r0 = blockIdx.x * 4;
    const int th = threadIdx.x;
    __shared__ float rs[4][256];
    __shared__ float sred[256];
    for (int k = 0; k < 4; k++) rs[k][th] = res_t[(size_t)(r0 + k) * HH + th];
    __syncthreads();
    float acc[4][4];
    #pragma unroll
    for (int r = 0; r < 4; r++)
        #pragma unroll
        for (int q = 0; q < 4; q++) acc[r][q] = tb3[th + q * 256];
    for (int h = 0; h < HH; h++) {
        float w0 = tw3[(size_t)h * CC + th];
        float w1 = tw3[(size_t)h * CC + th + 256];
        float w2 = tw3[(size_t)h * CC + th + 512];
        float w3 = tw3[(size_t)h * CC + th + 768];
        #pragma unroll
        for (int r = 0; r < 4; r++) {
            float xv = rs[r][h];
            acc[r][0] = fmaf(xv, w0, acc[r][0]);
            acc[r][1] = fmaf(xv, w1, acc[r][1]);
            acc[r][2] = fmaf(xv, w2, acc[r][2]);
            acc[r][3] = fmaf(xv, w3, acc[r][3]);
        }
    }
    for (int r = 0; r < 4; r++) {
        float m = fmaxf(fmaxf(acc[r][0], acc[r][1]), fmaxf(acc[r][2], acc[r][3]));
        sred[th] = m; __syncthreads();
        for (int off = 128; off > 0; off >>= 1) { if (th < off) sred[th] = fmaxf(sred[th], sred[th + off]); __syncthreads(); }
        float rm = sred[0]; __syncthreads();
        float ssum = __expf(acc[r][0] - rm) + __expf(acc[r][1] - rm) + __expf(acc[r][2] - rm) + __expf(acc[r][3] - rm);
        sred[th] = ssum; __syncthreads();
        for (int off = 128; off > 0; off >>= 1) { if (th < off) sred[th] += sred[th + off]; __syncthreads(); }
        float inv = 1.0f / sred[0]; __syncthreads();
        #pragma unroll
        for (int q = 0; q < 4; q++) {
            float p = __expf(acc[r][q] - rm) * inv;
            PB[(size_t)(th + q * 256) * CC + (r0 + r)] = f2bf(p);   // [j][i]
        }
    }
}

// ---------------- emission logits bf16 + per-chunk LSE partials ----------------
__global__ __launch_bounds__(256) void k_emit(const float* __restrict__ res_e,
                                              const float* __restrict__ ew3,
                                              const float* __restrict__ eb3,
                                              unsigned short* __restrict__ emitT,
                                              float* __restrict__ epart)
{
    const int ct = blockIdx.x >> 2, jc = blockIdx.x & 3;
    const int c0 = ct * 16, j0 = jc * 2500;
    const int th = threadIdx.x;
    __shared__ float rs[256][24];
    __shared__ float sred[256];
    for (int k = 0; k < 16; k++) rs[th][k] = res_e[(size_t)(c0 + k) * HH + th];
    __syncthreads();
    float lm[16], ls[16];
    #pragma unroll
    for (int c = 0; c < 16; c++) { lm[c] = -1e30f; ls[c] = 0.f; }
    for (int it = 0; it < 10; it++) {
        int jo = it * 256 + th;
        if (jo < 2500) {
            int j = j0 + jo;
            float acc[16];
            float bb = eb3[j];
            #pragma unroll
            for (int c = 0; c < 16; c++) acc[c] = bb;
            for (int h = 0; h < HH; h++) {
                float wv = ew3[(size_t)h * VV + j];
                #pragma unroll
                for (int c = 0; c < 16; c++) acc[c] = fmaf(rs[h][c], wv, acc[c]);
            }
            #pragma unroll
            for (int c = 0; c < 16; c++) {
                emitT[(size_t)j * CC + c0 + c] = f2bf(acc[c]);
                float nm = fmaxf(lm[c], acc[c]);
                ls[c] = ls[c] * __expf(lm[c] - nm) + __expf(acc[c] - nm);
                lm[c] = nm;
            }
        }
    }
    for (int c = 0; c < 16; c++) {
        sred[th] = lm[c]; __syncthreads();
        for (int off = 128; off > 0; off >>= 1) { if (th < off) sred[th] = fmaxf(sred[th], sred[th + off]); __syncthreads(); }
        float gm = sred[0]; __syncthreads();
        sred[th] = (lm[c] > -1e29f) ? ls[c] * __expf(lm[c] - gm) : 0.f;
        __syncthreads();
        for (int off = 128; off > 0; off >>= 1) { if (th < off) sred[th] += sred[th + off]; __syncthreads(); }
        if (th == 0) {
            epart[((size_t)jc * CC + c0 + c) * 2]     = gm;
            epart[((size_t)jc * CC + c0 + c) * 2 + 1] = sred[0];
        }
        __syncthreads();
    }
}

// ---------------- combine epart -> lse[c] ----------------
__global__ __launch_bounds__(256) void k_lse(const float* __restrict__ epart,
                                             float* __restrict__ lse)
{
    int c = blockIdx.x * 256 + threadIdx.x;
    float M = -1e30f, S = 0.f;
    #pragma unroll
    for (int q = 0; q < 4; q++) {
        float m  = epart[((size_t)q * CC + c) * 2];
        float s2 = epart[((size_t)q * CC + c) * 2 + 1];
        float nm = fmaxf(M, m);
        S = S * __expf(M - nm) + s2 * __expf(m - nm);
        M = nm;
    }
    lse[c] = M + __logf(S);
}

// ---------------- in-place: emitT logits -> eprob = exp(logit - lse[c]) ----------------
__global__ __launch_bounds__(256) void k_eprob(unsigned short* __restrict__ emitT,
                                               const float* __restrict__ lse)
{
    __shared__ float ls[1024];
    const int th = threadIdx.x;
    for (int i = th; i < 1024; i += 256) ls[i] = lse[i];
    __syncthreads();
    size_t base = ((size_t)blockIdx.x * 256 + th) * 8;
    int c0 = (int)(base & 1023);
    s8b v = *(const s8b*)(emitT + base);
    unsigned short o[8];
    #pragma unroll
    for (int e = 0; e < 8; e++)
        o[e] = f2bf(__expf(bf2f((unsigned short)v[e]) - ls[c0 + e]));
    s8b ov;
    #pragma unroll
    for (int e = 0; e < 8; e++) ov[e] = (short)o[e];
    *(s8b*)(emitT + base) = ov;
}

// ---------------- cross-block barrier (slot per step) ----------------
__device__ __forceinline__ void gbar(unsigned int* c)
{
    __syncthreads();   // compiler drains vmcnt before s_barrier -> all stores done
    if (threadIdx.x == 0) {
        __hip_atomic_fetch_add(c, 1u, __ATOMIC_RELEASE, __HIP_MEMORY_SCOPE_AGENT);
        while (__hip_atomic_load(c, __ATOMIC_ACQUIRE, __HIP_MEMORY_SCOPE_AGENT) < NB)
            __builtin_amdgcn_s_sleep(2);
    }
    __syncthreads();
}

// ---------------- forward scan: 16 blocks x 256 threads, P in registers ----------------
__global__ void __launch_bounds__(256, 1) k_fwd(
    const unsigned short* __restrict__ PB,    // [1024 j][1024 i] bf16
    const unsigned short* __restrict__ eprob, // [V][1024 c] bf16
    const float* __restrict__ slog,
    const int* __restrict__ text,
    unsigned short* __restrict__ vbuf,        // [2][16 n][1024 j] bf16
    float* __restrict__ parts,                // [2][16 blk][16 n]
    unsigned int* __restrict__ cnt,           // [256]
    float* __restrict__ outp)
{
    const int blk = blockIdx.x;
    const int th = threadIdx.x;
    const int w = th >> 6, l = th & 63;
    const int lhi = l >> 4, llo = l & 15;
    const int jglob = blk * 64 + w * 16 + llo;

    __shared__ int   toks[NN * TT];     // 16 KB
    __shared__ float ps_lds[256];
    __shared__ float sinv_lds[16];
    __shared__ float logacc[16];
    __shared__ float wpart[4][16];
    __shared__ float p0part[16];

    for (int i = th; i < NN * TT; i += 256) toks[i] = text[i];
    if (th < 16) logacc[th] = 0.f;

    // B fragments: wave's 16 columns, K=1024 -> 32 tiles, resident in VGPRs
    s8b bf[32];
    {
        const unsigned short* pbj = PB + (size_t)jglob * CC + lhi * 8;
        #pragma unroll
        for (int kt = 0; kt < 32; kt++)
            bf[kt] = *(const s8b*)(pbj + kt * 32);
    }

    // block-wide LSE of slog (start distribution)
    float x0 = slog[th], x1 = slog[th + 256], x2 = slog[th + 512], x3 = slog[th + 768];
    float mw = fmaxf(fmaxf(x0, x1), fmaxf(x2, x3));
    #pragma unroll
    for (int o = 32; o; o >>= 1) mw = fmaxf(mw, __shfl_xor(mw, o));
    if (l == 0) ps_lds[w] = mw;
    __syncthreads();
    float gm = fmaxf(fmaxf(ps_lds[0], ps_lds[1]), fmaxf(ps_lds[2], ps_lds[3]));
    __syncthreads();
    float e4 = __expf(x0 - gm) + __expf(x1 - gm) + __expf(x2 - gm) + __expf(x3 - gm);
    #pragma unroll
    for (int o = 32; o; o >>= 1) e4 += __shfl_xor(e4, o);
    if (l == 0) ps_lds[w] = e4;
    __syncthreads();
    float slse = gm + __logf(ps_lds[0] + ps_lds[1] + ps_lds[2] + ps_lds[3]);
    __syncthreads();

    // ---- t = 0: v0 = p0 * e0 for this block's 64 states ----
    {
        int jj = blk * 64 + l;
        float p0 = __expf(slog[jj] - slse);
        #pragma unroll
        for (int u = 0; u < 4; u++) {
            int nn2 = w * 4 + u;
            int tok = toks[nn2 * TT + 0];
            float v0 = p0 * bf2f(eprob[(size_t)tok * CC + jj]);
            float pv = __shfl_xor(v0, 1);
            if ((l & 1) == 0) {
                unsigned int pk = (unsigned int)f2bf(v0) | ((unsigned int)f2bf(pv) << 16);
                __hip_atomic_store((unsigned int*)(vbuf + (size_t)nn2 * CC + jj), pk,
                                   __ATOMIC_RELAXED, __HIP_MEMORY_SCOPE_AGENT);
            }
            float s = v0;
            #pragma unroll
            for (int o = 32; o; o >>= 1) s += __shfl_xor(s, o);
            if (l == 0) p0part[nn2] = s;
        }
    }
    __syncthreads();
    if (th < 16)
        __hip_atomic_store(parts + blk * 16 + th, p0part[th],
                           __ATOMIC_RELAXED, __HIP_MEMORY_SCOPE_AGENT);
    gbar(cnt + 0);

    // ---- main loop ----
    for (int t = 1; t < TT; t++) {
        const int prv = (t - 1) & 1, cur = t & 1;

        // stage partials, compute S_n and 1/S_n
        ps_lds[th] = __hip_atomic_load(parts + prv * 256 + th,
                                       __ATOMIC_RELAXED, __HIP_MEMORY_SCOPE_AGENT);
        __syncthreads();
        if (th < 16) {
            float S = 0.f;
            #pragma unroll
            for (int b = 0; b < 16; b++) S += ps_lds[b * 16 + th];
            sinv_lds[th] = 1.0f / S;
            if (blk == 0) logacc[th] += __logf(S);
        }

        // emission prefetch (independent of sinv)
        float epf[4];
        #pragma unroll
        for (int q = 0; q < 4; q++) {
            int tok = toks[(lhi * 4 + q) * TT + t];
            epf[q] = bf2f(eprob[(size_t)tok * CC + jglob]);
        }

        // A-fragments (agent-scope loads of raw v) + MFMA chain
        const unsigned short* vbase = vbuf + (size_t)prv * (NN * CC) + llo * CC + lhi * 8;
        f32x4 ac0 = {0,0,0,0}, ac1 = {0,0,0,0}, ac2 = {0,0,0,0}, ac3 = {0,0,0,0};
        #pragma unroll
        for (int kt = 0; kt < 32; kt += 4) {
            #pragma unroll
            for (int u = 0; u < 4; u++) {
                unsigned long long* p = (unsigned long long*)(vbase + (kt + u) * 32);
                unsigned long long d0 = __hip_atomic_load(p,     __ATOMIC_RELAXED, __HIP_MEMORY_SCOPE_AGENT);
                unsigned long long d1 = __hip_atomic_load(p + 1, __ATOMIC_RELAXED, __HIP_MEMORY_SCOPE_AGENT);
                s8b af;
                ((unsigned long long*)&af)[0] = d0;
                ((unsigned long long*)&af)[1] = d1;
                if (u == 0)      ac0 = __builtin_amdgcn_mfma_f32_16x16x32_bf16(af, bf[kt + u], ac0, 0, 0, 0);
                else if (u == 1) ac1 = __builtin_amdgcn_mfma_f32_16x16x32_bf16(af, bf[kt + u], ac1, 0, 0, 0);
                else if (u == 2) ac2 = __builtin_amdgcn_mfma_f32_16x16x32_bf16(af, bf[kt + u], ac2, 0, 0, 0);
                else             ac3 = __builtin_amdgcn_mfma_f32_16x16x32_bf16(af, bf[kt + u], ac3, 0, 0, 0);
            }
        }
        f32x4 acc = (ac0 + ac1) + (ac2 + ac3);
        __syncthreads();    // sinv_lds ready (overlapped with MFMA)

        // epilogue: scale, emit-multiply, column-sum, pack+store
        #pragma unroll
        for (int q = 0; q < 4; q++) {
            int nn2 = lhi * 4 + q;   // C/D: row = (lane>>4)*4 + reg, col = lane&15
            float vq = acc[q] * sinv_lds[nn2] * epf[q];
            float sp = vq;
            #pragma unroll
            for (int o = 1; o < 16; o <<= 1) sp += __shfl_xor(sp, o);
            if (llo == 0) wpart[w][nn2] = sp;
            float pv = __shfl_xor(vq, 1);
            if ((llo & 1) == 0) {
                unsigned int pk = (unsigned int)f2bf(vq) | ((unsigned int)f2bf(pv) << 16);
                __hip_atomic_store((unsigned int*)(vbuf + (size_t)cur * (NN * CC) + (size_t)nn2 * CC + jglob),
                                   pk, __ATOMIC_RELAXED, __HIP_MEMORY_SCOPE_AGENT);
            }
        }
        __syncthreads();
        if (th < 16) {
            float sp = wpart[0][th] + wpart[1][th] + wpart[2][th] + wpart[3][th];
            __hip_atomic_store(parts + cur * 256 + blk * 16 + th, sp,
                               __ATOMIC_RELAXED, __HIP_MEMORY_SCOPE_AGENT);
        }
        gbar(cnt + t);
    }

    // ---- final: block 0 folds last S and writes output ----
    if (blk == 0) {
        ps_lds[th] = __hip_atomic_load(parts + 256 + th,   // parity of t=255 is 1
                                       __ATOMIC_RELAXED, __HIP_MEMORY_SCOPE_AGENT);
        __syncthreads();
        if (th == 0) {
            float total = 0.f;
            for (int n = 0; n < 16; n++) {
                float S = 0.f;
                for (int b = 0; b < 16; b++) S += ps_lds[b * 16 + n];
                total += logacc[n] + __logf(S);
            }
            outp[0] = total;
        }
    }
}

extern "C" void kernel_launch(void* const* d_in, const int* in_sizes, int n_in,
                              void* d_out, int out_size, void* d_ws, size_t ws_size,
                              hipStream_t stream) {
    const int*   text      = (const int*)  d_in[0];
    const float* start_emb = (const float*)d_in[1];
    const float* sw1 = (const float*)d_in[2];
    const float* sb1 = (const float*)d_in[3];
    const float* sw2 = (const float*)d_in[4];
    const float* sb2 = (const float*)d_in[5];
    const float* sw3 = (const float*)d_in[6];
    const float* sb3 = (const float*)d_in[7];
    const float* state_emb = (const float*)d_in[8];
    const float* tw1 = (const float*)d_in[9];
    const float* tb1 = (const float*)d_in[10];
    const float* tw2 = (const float*)d_in[11];
    const float* tb2 = (const float*)d_in[12];
    const float* tw3 = (const float*)d_in[13];
    const float* tb3 = (const float*)d_in[14];
    const float* pre_emb = (const float*)d_in[15];
    const float* ew1 = (const float*)d_in[16];
    const float* eb1 = (const float*)d_in[17];
    const float* ew2 = (const float*)d_in[18];
    const float* eb2 = (const float*)d_in[19];
    const float* ew3 = (const float*)d_in[20];
    const float* eb3 = (const float*)d_in[21];

    char* wsp = (char*)d_ws;
    float* res_s = (float*)(wsp + (size_t)(0 << 20));
    float* res_t = (float*)(wsp + (size_t)(1 << 20));
    float* res_e = (float*)(wsp + (size_t)(2 << 20));
    float* slog  = (float*)(wsp + (size_t)(3 << 20));
    float* epart = (float*)(wsp + (size_t)(3 << 20) + 64 * 1024);
    float* lse   = (float*)(wsp + (size_t)(3 << 20) + 128 * 1024);
    float* parts = (float*)(wsp + (size_t)(3 << 20) + 192 * 1024);
    unsigned int* cnt = (unsigned int*)(wsp + (size_t)(3 << 20) + 256 * 1024);
    unsigned short* vbuf = (unsigned short*)(wsp + (size_t)(3 << 20) + 320 * 1024);
    unsigned short* PB   = (unsigned short*)(wsp + (size_t)(4 << 20));   // 2 MB
    unsigned short* emitT = (unsigned short*)(wsp + (size_t)(6 << 20));  // 20.48 MB (logits -> probs in place)
    float* outp  = (float*)d_out;

    if (ws_size < ((size_t)27 << 20)) return;  // leaves poison -> visible failure

    hipMemsetAsync(cnt, 0, 256 * sizeof(unsigned int), stream);

    ResArgs3 ra;
    ra.a[0] = { start_emb, sw1, sb1, sw2, sb2, res_s };
    ra.a[1] = { state_emb, tw1, tb1, tw2, tb2, res_t };
    ra.a[2] = { pre_emb,   ew1, eb1, ew2, eb2, res_e };

    hipLaunchKernelGGL(k_res,   dim3(64, 3), dim3(256), 0, stream, ra);
    hipLaunchKernelGGL(k_slog,  dim3(4),     dim3(256), 0, stream, res_s, sw3, sb3, slog);
    hipLaunchKernelGGL(k_pt,    dim3(256),   dim3(256), 0, stream, res_t, tw3, tb3, PB);
    hipLaunchKernelGGL(k_emit,  dim3(256),   dim3(256), 0, stream, res_e, ew3, eb3, emitT, epart);
    hipLaunchKernelGGL(k_lse,   dim3(4),     dim3(256), 0, stream, epart, lse);
    hipLaunchKernelGGL(k_eprob, dim3(5000),  dim3(256), 0, stream, emitT, lse);
    hipLaunchKernelGGL(k_fwd,   dim3(NB),    dim3(256), 0, stream,
                       PB, emitT, slog, text, vbuf, parts, cnt, outp);
}

// Round 4
// 2076.095 us; speedup vs baseline: 7.9402x; 1.3907x over previous
//
#include <hip/hip_runtime.h>
#include <hip/hip_bf16.h>
#include <cstddef>

#define CC 1024   // states
#define HH 256    // hidden
#define VV 10000  // vocab
#define NN 16     // batch
#define TT 256    // time
#define NB 16     // blocks in k_fwd

typedef __attribute__((ext_vector_type(8))) short s8b;
typedef __attribute__((ext_vector_type(4))) float f32x4;

__device__ __forceinline__ unsigned short f2bf(float f) {
    unsigned int b = __builtin_bit_cast(unsigned int, f);
    b += 0x7FFFu + ((b >> 16) & 1u);
    return (unsigned short)(b >> 16);
}
__device__ __forceinline__ float bf2f(unsigned short u) {
    return __builtin_bit_cast(float, ((unsigned int)u) << 16);
}

// ---------------- residual MLP: out = relu(relu(x@w1+b1)@w2+b2) + x ----------------
struct ResArgs { const float *x, *w1, *b1, *w2, *b2; float* o; };
struct ResArgs3 { ResArgs a[3]; };

__global__ __launch_bounds__(256) void k_res(ResArgs3 A)
{
    ResArgs R = A.a[blockIdx.y];
    const int r0 = blockIdx.x * 16;
    const int th = threadIdx.x;
    __shared__ float xs[256][24];
    __shared__ float hs[256][24];
    #pragma unroll
    for (int k = 0; k < 16; k++) xs[th][k] = R.x[(size_t)(r0 + k) * HH + th];
    __syncthreads();
    float acc[16];
    float b1v = R.b1[th];
    #pragma unroll
    for (int r = 0; r < 16; r++) acc[r] = b1v;
    for (int h = 0; h < HH; h++) {
        float w = R.w1[(size_t)h * HH + th];
        #pragma unroll
        for (int r = 0; r < 16; r++) acc[r] = fmaf(xs[h][r], w, acc[r]);
    }
    #pragma unroll
    for (int r = 0; r < 16; r++) hs[th][r] = fmaxf(acc[r], 0.f);
    __syncthreads();
    float b2v = R.b2[th];
    #pragma unroll
    for (int r = 0; r < 16; r++) acc[r] = b2v;
    for (int h = 0; h < HH; h++) {
        float w = R.w2[(size_t)h * HH + th];
        #pragma unroll
        for (int r = 0; r < 16; r++) acc[r] = fmaf(hs[h][r], w, acc[r]);
    }
    #pragma unroll
    for (int r = 0; r < 16; r++) {
        size_t idx = (size_t)(r0 + r) * HH + th;
        R.o[idx] = fmaxf(acc[r], 0.f) + R.x[idx];
    }
}

// ---------------- start logits ----------------
__global__ __launch_bounds__(256) void k_slog(const float* __restrict__ res_s,
                                              const float* __restrict__ sw3,
                                              const float* __restrict__ sb3,
                                              float* __restrict__ slog)
{
    __shared__ float wv[256];
    const int th = threadIdx.x;
    const int c = blockIdx.x * 256 + th;
    wv[th] = sw3[th];
    __syncthreads();
    const float* row = res_s + (size_t)c * HH;
    float acc = 0.f;
    for (int h = 0; h < HH; h++) acc = fmaf(row[h], wv[h], acc);
    slog[c] = acc + sb3[0];
}

// ---------------- transition probs, transposed bf16: PB[j][i] = p(j | i) ----------------
__global__ __launch_bounds__(256) void k_pt(const float* __restrict__ res_t,
                                            const float* __restrict__ tw3,
                                            const float* __restrict__ tb3,
                                            unsigned short* __restrict__ PB)
{
    const int r0 = blockIdx.x * 4;
    const int th = threadIdx.x;
    __shared__ float rs[4][256];
    __shared__ float sred[256];
    for (int k = 0; k < 4; k++) rs[k][th] = res_t[(size_t)(r0 + k) * HH + th];
    __syncthreads();
    float acc[4][4];
    #pragma unroll
    for (int r = 0; r < 4; r++)
        #pragma unroll
        for (int q = 0; q < 4; q++) acc[r][q] = tb3[th + q * 256];
    for (int h = 0; h < HH; h++) {
        float w0 = tw3[(size_t)h * CC + th];
        float w1 = tw3[(size_t)h * CC + th + 256];
        float w2 = tw3[(size_t)h * CC + th + 512];
        float w3 = tw3[(size_t)h * CC + th + 768];
        #pragma unroll
        for (int r = 0; r < 4; r++) {
            float xv = rs[r][h];
            acc[r][0] = fmaf(xv, w0, acc[r][0]);
            acc[r][1] = fmaf(xv, w1, acc[r][1]);
            acc[r][2] = fmaf(xv, w2, acc[r][2]);
            acc[r][3] = fmaf(xv, w3, acc[r][3]);
        }
    }
    for (int r = 0; r < 4; r++) {
        float m = fmaxf(fmaxf(acc[r][0], acc[r][1]), fmaxf(acc[r][2], acc[r][3]));
        sred[th] = m; __syncthreads();
        for (int off = 128; off > 0; off >>= 1) { if (th < off) sred[th] = fmaxf(sred[th], sred[th + off]); __syncthreads(); }
        float rm = sred[0]; __syncthreads();
        float ssum = __expf(acc[r][0] - rm) + __expf(acc[r][1] - rm) + __expf(acc[r][2] - rm) + __expf(acc[r][3] - rm);
        sred[th] = ssum; __syncthreads();
        for (int off = 128; off > 0; off >>= 1) { if (th < off) sred[th] += sred[th + off]; __syncthreads(); }
        float inv = 1.0f / sred[0]; __syncthreads();
        #pragma unroll
        for (int q = 0; q < 4; q++) {
            float p = __expf(acc[r][q] - rm) * inv;
            PB[(size_t)(th + q * 256) * CC + (r0 + r)] = f2bf(p);   // [j][i]
        }
    }
}

// ---------------- emission logits bf16 + per-chunk LSE partials ----------------
__global__ __launch_bounds__(256) void k_emit(const float* __restrict__ res_e,
                                              const float* __restrict__ ew3,
                                              const float* __restrict__ eb3,
                                              unsigned short* __restrict__ emitT,
                                              float* __restrict__ epart)
{
    const int ct = blockIdx.x >> 2, jc = blockIdx.x & 3;
    const int c0 = ct * 16, j0 = jc * 2500;
    const int th = threadIdx.x;
    __shared__ float rs[256][24];
    __shared__ float sred[256];
    for (int k = 0; k < 16; k++) rs[th][k] = res_e[(size_t)(c0 + k) * HH + th];
    __syncthreads();
    float lm[16], ls[16];
    #pragma unroll
    for (int c = 0; c < 16; c++) { lm[c] = -1e30f; ls[c] = 0.f; }
    for (int it = 0; it < 10; it++) {
        int jo = it * 256 + th;
        if (jo < 2500) {
            int j = j0 + jo;
            float acc[16];
            float bb = eb3[j];
            #pragma unroll
            for (int c = 0; c < 16; c++) acc[c] = bb;
            for (int h = 0; h < HH; h++) {
                float wv = ew3[(size_t)h * VV + j];
                #pragma unroll
                for (int c = 0; c < 16; c++) acc[c] = fmaf(rs[h][c], wv, acc[c]);
            }
            #pragma unroll
            for (int c = 0; c < 16; c++) {
                emitT[(size_t)j * CC + c0 + c] = f2bf(acc[c]);
                float nm = fmaxf(lm[c], acc[c]);
                ls[c] = ls[c] * __expf(lm[c] - nm) + __expf(acc[c] - nm);
                lm[c] = nm;
            }
        }
    }
    for (int c = 0; c < 16; c++) {
        sred[th] = lm[c]; __syncthreads();
        for (int off = 128; off > 0; off >>= 1) { if (th < off) sred[th] = fmaxf(sred[th], sred[th + off]); __syncthreads(); }
        float gm = sred[0]; __syncthreads();
        sred[th] = (lm[c] > -1e29f) ? ls[c] * __expf(lm[c] - gm) : 0.f;
        __syncthreads();
        for (int off = 128; off > 0; off >>= 1) { if (th < off) sred[th] += sred[th + off]; __syncthreads(); }
        if (th == 0) {
            epart[((size_t)jc * CC + c0 + c) * 2]     = gm;
            epart[((size_t)jc * CC + c0 + c) * 2 + 1] = sred[0];
        }
        __syncthreads();
    }
}

// ---------------- combine epart -> lse[c] ----------------
__global__ __launch_bounds__(256) void k_lse(const float* __restrict__ epart,
                                             float* __restrict__ lse)
{
    int c = blockIdx.x * 256 + threadIdx.x;
    float M = -1e30f, S = 0.f;
    #pragma unroll
    for (int q = 0; q < 4; q++) {
        float m  = epart[((size_t)q * CC + c) * 2];
        float s2 = epart[((size_t)q * CC + c) * 2 + 1];
        float nm = fmaxf(M, m);
        S = S * __expf(M - nm) + s2 * __expf(m - nm);
        M = nm;
    }
    lse[c] = M + __logf(S);
}

// ---------------- in-place: emitT logits -> eprob = exp(logit - lse[c]) ----------------
__global__ __launch_bounds__(256) void k_eprob(unsigned short* __restrict__ emitT,
                                               const float* __restrict__ lse)
{
    __shared__ float ls[1024];
    const int th = threadIdx.x;
    for (int i = th; i < 1024; i += 256) ls[i] = lse[i];
    __syncthreads();
    size_t base = ((size_t)blockIdx.x * 256 + th) * 8;
    int c0 = (int)(base & 1023);
    s8b v = *(const s8b*)(emitT + base);
    unsigned short o[8];
    #pragma unroll
    for (int e = 0; e < 8; e++)
        o[e] = f2bf(__expf(bf2f((unsigned short)v[e]) - ls[c0 + e]));
    s8b ov;
    #pragma unroll
    for (int e = 0; e < 8; e++) ov[e] = (short)o[e];
    *(s8b*)(emitT + base) = ov;
}

// ---------------- forward scan: 16 blocks x 256 threads, P in registers ----------------
// Sync protocol: block b sets flags[t][b] = t+1 after draining (vmcnt 0) its
// sc0/sc1 write-through stores of step t. A block at step t polls flags[t-1][*]
// == t, which implies (a) all step t-1 data visible at the coherence point and
// (b) everyone finished READING buffer parity t&1 -> safe to overwrite it.
__global__ void __launch_bounds__(256, 1) k_fwd(
    const unsigned short* __restrict__ PB,    // [1024 j][1024 i] bf16
    const unsigned short* __restrict__ eprob, // [V][1024 c] bf16
    const float* __restrict__ slog,
    const int* __restrict__ text,
    unsigned short* __restrict__ vbuf,        // [2][16 n][1024 j] bf16
    float* __restrict__ parts,                // [2][16 blk][16 n]
    unsigned int* __restrict__ flags,         // [256 t][16 blk]
    float* __restrict__ outp)
{
    const int blk = blockIdx.x;
    const int th = threadIdx.x;
    const int w = th >> 6, l = th & 63;
    const int lhi = l >> 4, llo = l & 15;
    const int jglob = blk * 64 + w * 16 + llo;

    __shared__ int   toks[NN * TT];     // 16 KB
    __shared__ float ps_lds[256];
    __shared__ float sinv_lds[16];
    __shared__ float logacc[16];
    __shared__ float wpart[4][16];
    __shared__ float p0part[16];
    __shared__ __align__(16) unsigned short vtile[16][64];   // [n][j-slice]

    for (int i = th; i < NN * TT; i += 256) toks[i] = text[i];
    if (th < 16) logacc[th] = 0.f;

    // B fragments: wave's 16 columns, K=1024 -> 32 tiles, resident in VGPRs
    s8b bf[32];
    {
        const unsigned short* pbj = PB + (size_t)jglob * CC + lhi * 8;
        #pragma unroll
        for (int kt = 0; kt < 32; kt++)
            bf[kt] = *(const s8b*)(pbj + kt * 32);
    }

    // block-wide LSE of slog (start distribution)
    float x0 = slog[th], x1 = slog[th + 256], x2 = slog[th + 512], x3 = slog[th + 768];
    float mw = fmaxf(fmaxf(x0, x1), fmaxf(x2, x3));
    #pragma unroll
    for (int o = 32; o; o >>= 1) mw = fmaxf(mw, __shfl_xor(mw, o));
    if (l == 0) ps_lds[w] = mw;
    __syncthreads();
    float gm = fmaxf(fmaxf(ps_lds[0], ps_lds[1]), fmaxf(ps_lds[2], ps_lds[3]));
    __syncthreads();
    float e4 = __expf(x0 - gm) + __expf(x1 - gm) + __expf(x2 - gm) + __expf(x3 - gm);
    #pragma unroll
    for (int o = 32; o; o >>= 1) e4 += __shfl_xor(e4, o);
    if (l == 0) ps_lds[w] = e4;
    __syncthreads();
    float slse = gm + __logf(ps_lds[0] + ps_lds[1] + ps_lds[2] + ps_lds[3]);
    __syncthreads();

    // ---- t = 0: v0 = p0 * e0 for this block's 64 states ----
    {
        int jj = blk * 64 + l;
        float p0 = __expf(slog[jj] - slse);
        #pragma unroll
        for (int u = 0; u < 4; u++) {
            int nn2 = w * 4 + u;
            int tok = toks[nn2 * TT + 0];
            float v0 = p0 * bf2f(eprob[(size_t)tok * CC + jj]);
            float pv = __shfl_xor(v0, 1);
            if ((l & 1) == 0) {
                unsigned int pk = (unsigned int)f2bf(v0) | ((unsigned int)f2bf(pv) << 16);
                __hip_atomic_store((unsigned int*)(vbuf + (size_t)nn2 * CC + jj), pk,
                                   __ATOMIC_RELAXED, __HIP_MEMORY_SCOPE_AGENT);
            }
            float s = v0;
            #pragma unroll
            for (int o = 32; o; o >>= 1) s += __shfl_xor(s, o);
            if (l == 0) p0part[nn2] = s;
        }
    }
    __syncthreads();
    if (th < 16)
        __hip_atomic_store(parts + blk * 16 + th, p0part[th],
                           __ATOMIC_RELAXED, __HIP_MEMORY_SCOPE_AGENT);
    asm volatile("s_waitcnt vmcnt(0)" ::: "memory");
    __syncthreads();
    if (th == 0)
        __hip_atomic_store(&flags[0 * 16 + blk], 1u,
                           __ATOMIC_RELAXED, __HIP_MEMORY_SCOPE_AGENT);

    // ---- main loop ----
    for (int t = 1; t < TT; t++) {
        const int prv = (t - 1) & 1, cur = t & 1;

        // emission gather for this step (read-only table, doesn't need the flag)
        float epf[4];
        #pragma unroll
        for (int q = 0; q < 4; q++) {
            int tok = toks[(lhi * 4 + q) * TT + t];
            epf[q] = bf2f(eprob[(size_t)tok * CC + jglob]);
        }

        // wait for all blocks' step t-1 publication
        if (th < 16) {
            while (__hip_atomic_load(&flags[(t - 1) * 16 + th],
                                     __ATOMIC_RELAXED, __HIP_MEMORY_SCOPE_AGENT)
                   != (unsigned int)t) {}
        }
        __syncthreads();

        // bulk A-fragment loads (coherent, bypass L1/L2) - all 32 in flight
        const unsigned short* vbase = vbuf + (size_t)prv * (NN * CC) + (size_t)llo * CC + lhi * 8;
        s8b af[32];
        #pragma unroll
        for (int kt = 0; kt < 32; kt++) {
            asm volatile("global_load_dwordx4 %0, %1, off offset:%2 sc0 sc1"
                         : "=v"(af[kt]) : "v"(vbase), "n"(kt * 64));
        }
        float pval;
        asm volatile("global_load_dword %0, %1, off sc0 sc1"
                     : "=v"(pval) : "v"(parts + (size_t)prv * 256 + th));
        asm volatile("s_waitcnt vmcnt(0)" ::: "memory");
        __builtin_amdgcn_sched_barrier(0);

        ps_lds[th] = pval;
        __syncthreads();
        if (th < 16) {
            float S = 0.f;
            #pragma unroll
            for (int b = 0; b < 16; b++) S += ps_lds[b * 16 + th];
            sinv_lds[th] = 1.0f / S;
            if (blk == 0) logacc[th] += __logf(S);
        }

        // MFMA chain: 4 independent accumulators
        f32x4 ac0 = {0,0,0,0}, ac1 = {0,0,0,0}, ac2 = {0,0,0,0}, ac3 = {0,0,0,0};
        #pragma unroll
        for (int kt = 0; kt < 32; kt += 4) {
            ac0 = __builtin_amdgcn_mfma_f32_16x16x32_bf16(af[kt + 0], bf[kt + 0], ac0, 0, 0, 0);
            ac1 = __builtin_amdgcn_mfma_f32_16x16x32_bf16(af[kt + 1], bf[kt + 1], ac1, 0, 0, 0);
            ac2 = __builtin_amdgcn_mfma_f32_16x16x32_bf16(af[kt + 2], bf[kt + 2], ac2, 0, 0, 0);
            ac3 = __builtin_amdgcn_mfma_f32_16x16x32_bf16(af[kt + 3], bf[kt + 3], ac3, 0, 0, 0);
        }
        f32x4 acc = (ac0 + ac1) + (ac2 + ac3);
        __syncthreads();    // sinv_lds ready

        // epilogue: scale, emit-multiply, per-n partial sums, stage v into LDS
        #pragma unroll
        for (int q = 0; q < 4; q++) {
            int nn2 = lhi * 4 + q;   // C/D: row = (lane>>4)*4 + reg, col = lane&15
            float vq = acc[q] * sinv_lds[nn2] * epf[q];
            float sp = vq;
            #pragma unroll
            for (int o = 1; o < 16; o <<= 1) sp += __shfl_xor(sp, o);
            if (llo == 0) wpart[w][nn2] = sp;
            vtile[nn2][w * 16 + llo] = f2bf(vq);
        }
        __syncthreads();

        // coalesced publication: 128 lanes store 16B each (block's 64-j slice, all 16 n)
        if (th < 128) {
            int n = th >> 3, seg = th & 7;
            s8b val = *(const s8b*)&vtile[n][seg * 8];
            unsigned short* dst = vbuf + (size_t)cur * (NN * CC) + (size_t)n * CC + blk * 64 + seg * 8;
            asm volatile("global_store_dwordx4 %0, %1, off sc0 sc1"
                         :: "v"(dst), "v"(val) : "memory");
        }
        if (th < 16) {
            float sp = wpart[0][th] + wpart[1][th] + wpart[2][th] + wpart[3][th];
            float* dst = parts + (size_t)cur * 256 + blk * 16 + th;
            asm volatile("global_store_dword %0, %1, off sc0 sc1"
                         :: "v"(dst), "v"(sp) : "memory");
        }
        asm volatile("s_waitcnt vmcnt(0)" ::: "memory");
        __syncthreads();
        if (th == 0)
            __hip_atomic_store(&flags[t * 16 + blk], (unsigned int)(t + 1),
                               __ATOMIC_RELAXED, __HIP_MEMORY_SCOPE_AGENT);
    }

    // ---- final: block 0 folds last S and writes output ----
    if (blk == 0) {
        if (th < 16) {
            while (__hip_atomic_load(&flags[255 * 16 + th],
                                     __ATOMIC_RELAXED, __HIP_MEMORY_SCOPE_AGENT) != 256u) {}
        }
        __syncthreads();
        ps_lds[th] = __hip_atomic_load(parts + 256 + th,   // parity of t=255 is 1
                                       __ATOMIC_RELAXED, __HIP_MEMORY_SCOPE_AGENT);
        __syncthreads();
        if (th == 0) {
            float total = 0.f;
            for (int n = 0; n < 16; n++) {
                float S = 0.f;
                for (int b = 0; b < 16; b++) S += ps_lds[b * 16 + n];
                total += logacc[n] + __logf(S);
            }
            outp[0] = total;
        }
    }
}

extern "C" void kernel_launch(void* const* d_in, const int* in_sizes, int n_in,
                              void* d_out, int out_size, void* d_ws, size_t ws_size,
                              hipStream_t stream) {
    const int*   text      = (const int*)  d_in[0];
    const float* start_emb = (const float*)d_in[1];
    const float* sw1 = (const float*)d_in[2];
    const float* sb1 = (const float*)d_in[3];
    const float* sw2 = (const float*)d_in[4];
    const float* sb2 = (const float*)d_in[5];
    const float* sw3 = (const float*)d_in[6];
    const float* sb3 = (const float*)d_in[7];
    const float* state_emb = (const float*)d_in[8];
    const float* tw1 = (const float*)d_in[9];
    const float* tb1 = (const float*)d_in[10];
    const float* tw2 = (const float*)d_in[11];
    const float* tb2 = (const float*)d_in[12];
    const float* tw3 = (const float*)d_in[13];
    const float* tb3 = (const float*)d_in[14];
    const float* pre_emb = (const float*)d_in[15];
    const float* ew1 = (const float*)d_in[16];
    const float* eb1 = (const float*)d_in[17];
    const float* ew2 = (const float*)d_in[18];
    const float* eb2 = (const float*)d_in[19];
    const float* ew3 = (const float*)d_in[20];
    const float* eb3 = (const float*)d_in[21];

    char* wsp = (char*)d_ws;
    float* res_s = (float*)(wsp + (size_t)(0 << 20));
    float* res_t = (float*)(wsp + (size_t)(1 << 20));
    float* res_e = (float*)(wsp + (size_t)(2 << 20));
    float* slog  = (float*)(wsp + (size_t)(3 << 20));
    float* epart = (float*)(wsp + (size_t)(3 << 20) + 64 * 1024);
    float* lse   = (float*)(wsp + (size_t)(3 << 20) + 128 * 1024);
    float* parts = (float*)(wsp + (size_t)(3 << 20) + 192 * 1024);
    unsigned int* flags = (unsigned int*)(wsp + (size_t)(3 << 20) + 256 * 1024);  // 16 KB
    unsigned short* vbuf = (unsigned short*)(wsp + (size_t)(3 << 20) + 320 * 1024);
    unsigned short* PB   = (unsigned short*)(wsp + (size_t)(4 << 20));   // 2 MB
    unsigned short* emitT = (unsigned short*)(wsp + (size_t)(6 << 20));  // 20.48 MB (logits -> probs in place)
    float* outp  = (float*)d_out;

    if (ws_size < ((size_t)27 << 20)) return;  // leaves poison -> visible failure

    hipMemsetAsync(flags, 0, TT * NB * sizeof(unsigned int), stream);

    ResArgs3 ra;
    ra.a[0] = { start_emb, sw1, sb1, sw2, sb2, res_s };
    ra.a[1] = { state_emb, tw1, tb1, tw2, tb2, res_t };
    ra.a[2] = { pre_emb,   ew1, eb1, ew2, eb2, res_e };

    hipLaunchKernelGGL(k_res,   dim3(64, 3), dim3(256), 0, stream, ra);
    hipLaunchKernelGGL(k_slog,  dim3(4),     dim3(256), 0, stream, res_s, sw3, sb3, slog);
    hipLaunchKernelGGL(k_pt,    dim3(256),   dim3(256), 0, stream, res_t, tw3, tb3, PB);
    hipLaunchKernelGGL(k_emit,  dim3(256),   dim3(256), 0, stream, res_e, ew3, eb3, emitT, epart);
    hipLaunchKernelGGL(k_lse,   dim3(4),     dim3(256), 0, stream, epart, lse);
    hipLaunchKernelGGL(k_eprob, dim3(5000),  dim3(256), 0, stream, emitT, lse);
    hipLaunchKernelGGL(k_fwd,   dim3(NB),    dim3(256), 0, stream,
                       PB, emitT, slog, text, vbuf, parts, flags, outp);
}